// Round 9
// baseline (133.035 us; speedup 1.0000x reference)
//
#include <hip/hip_runtime.h>
#include <stdint.h>

#define N_PTS 131072
#define NCLS 8
#define HID 256
#define MT 32      // points per tile; 256-thread blocks -> ~6 independent blocks/CU
#define CAP 32768  // per-class sortedIdx capacity (counts ~16.4k for this input)

// prescale: tanh(z) computed as 1 - 2/(exp2(PSC*z)+1), PSC = 2*log2(e)
#define PSC 2.8853900817779268f

typedef __bf16 bf16x8 __attribute__((ext_vector_type(8)));
typedef float f32x4 __attribute__((ext_vector_type(4)));

// tanh from a = PSC*z: tanh = 1 - 2/(2^a + 1); v_exp_f32 is 2^x natively
__device__ __forceinline__ float tanh_p2(float a) {
  return fmaf(-2.0f, __builtin_amdgcn_rcpf(__builtin_amdgcn_exp2f(a) + 1.0f), 1.0f);
}

__device__ __forceinline__ unsigned short f2bf_rne(float f) {
  unsigned u = __float_as_uint(f);
  u = u + 0x7fffu + ((u >> 16) & 1u);
  return (unsigned short)(u >> 16);
}

// pack two floats to bf16 pair (round-half-up): {hi16(b), hi16(a)}
__device__ __forceinline__ unsigned pack_bf16(float a, float b) {
  unsigned ua = __float_as_uint(a) + 0x8000u;
  unsigned ub = __float_as_uint(b) + 0x8000u;
  return __builtin_amdgcn_perm(ub, ua, 0x07060302u);
}

// ---------------- fused prep kernel (unchanged, R4-proven) ----------------
#define PK_TILES 256
#define MISC_BLKS 177
#define MISC_N 45184
#define SCAT_BLKS 128   // 1024 points/block, ballot-ranked, 1 atomic instr/block
#define PREP_GRID (PK_TILES + MISC_BLKS + SCAT_BLKS)

__global__ __launch_bounds__(256) void k_prep(
    const int* __restrict__ times,
    const float* __restrict__ W1, const float* __restrict__ b1,
    const float* __restrict__ W2, const float* __restrict__ b2,
    const float* __restrict__ W3, const float* __restrict__ b3,
    const float* __restrict__ W4, const float* __restrict__ b4,
    int* __restrict__ hdr, int* __restrict__ sortedIdx,
    unsigned short* __restrict__ packed23,
    float* __restrict__ w1p, float* __restrict__ b2p,
    float* __restrict__ b3p, float* __restrict__ b4p,
    unsigned short* __restrict__ W4p) {
  __shared__ unsigned short T[64][64];  // 8 KB transpose tile

  int b = blockIdx.x;
  int tid = threadIdx.x;

  if (b < PK_TILES) {
    // ---- tiled transpose-pack of W2/W3 into MFMA A-frag layout ----
    int cl = b >> 4;            // 0..15 class-layer
    int l = cl >> 3, c = cl & 7;
    int tile = b & 15;
    int k0 = (tile >> 2) * 64, j0 = (tile & 3) * 64;
    const float* W = (l ? W3 : W2) + c * 65536;
#pragma unroll
    for (int it = 0; it < 4; it++) {
      int f = tid + it * 256;        // 0..1023 float4 slots
      int row = f >> 4, cg = f & 15;
      float4 v = *(const float4*)&W[(k0 + row) * 256 + j0 + cg * 4];
      T[row][cg * 4 + 0] = f2bf_rne(PSC * v.x);
      T[row][cg * 4 + 1] = f2bf_rne(PSC * v.y);
      T[row][cg * 4 + 2] = f2bf_rne(PSC * v.z);
      T[row][cg * 4 + 3] = f2bf_rne(PSC * v.w);
    }
    __syncthreads();
#pragma unroll
    for (int it = 0; it < 2; it++) {
      int g = tid + it * 256;        // 0..511: kb = g>>6, j = g&63
      int kb = g >> 6, j = g & 63;
      unsigned u[8];
#pragma unroll
      for (int uu = 0; uu < 8; uu++) u[uu] = T[kb * 8 + uu][j];
      uint4 pk = make_uint4(u[0] | (u[1] << 16), u[2] | (u[3] << 16),
                            u[4] | (u[5] << 16), u[6] | (u[7] << 16));
      int base = cl * 65536 + (((k0 >> 3) + kb) * 256 + (j0 + j)) * 8;
      *(uint4*)&packed23[base] = pk;
    }
  } else if (b < PK_TILES + MISC_BLKS) {
    // ---- misc pack: w1p, b2p, b3p, b4p, W4p (all prescaled by PSC) ----
    int e2 = (b - PK_TILES) * 256 + tid;
    if (e2 < 8192) {          // w1p: [c][j][4] = {w0,w1,w2,b} * PSC
      int c = e2 >> 10, rem = e2 & 1023;
      int j = rem >> 2, t = rem & 3;
      float v = (t < 3) ? W1[c * 768 + t * 256 + j] : b1[c * 256 + j];
      w1p[e2] = PSC * v;
    } else if (e2 < 10240) {
      int i = e2 - 8192;
      b2p[i] = PSC * b2[i];
    } else if (e2 < 12288) {
      int i = e2 - 10240;
      b3p[i] = PSC * b3[i];
    } else if (e2 < 12416) {  // b4p: [c][16]
      int i = e2 - 12288;
      int c = i >> 4, r = i & 15;
      b4p[i] = (r < 3) ? PSC * b4[c * 3 + r] : 0.0f;
    } else if (e2 < MISC_N) { // W4p: [c][k/8][j(16)][k%8]
      int i = e2 - 12416;
      int c = i >> 12, rem = i & 4095;
      int jj = rem & 7, j = (rem >> 3) & 15, k = ((rem >> 7) << 3) + jj;
      float v = (j < 3) ? PSC * W4[c * 768 + k * 3 + j] : 0.0f;
      W4p[c * 4096 + rem] = f2bf_rne(v);
    }
  } else {
    // ---- scatter-append: ballot-ranked, zero LDS atomics,
    //      ONE global-atomic instruction per block (8 lanes, hdr[0..7]) ----
    __shared__ int gcnt[16][NCLS];  // per (wave,slot) histograms
    __shared__ int gpre[16][NCLS];  // exclusive prefix per class
    __shared__ int gbase[NCLS];     // block base in global per-class region
    int sb = b - (PK_TILES + MISC_BLKS);
    int lane = tid & 63, w = tid >> 6;
    int4 tv = ((const int4*)times)[sb * 256 + tid];  // 4 points per thread
    int tcl[4] = {tv.x, tv.y, tv.z, tv.w};
    int rank[4];
#pragma unroll
    for (int s = 0; s < 4; s++) {
      int t = tcl[s];
      unsigned long long m0 = __ballot(t == 0), m1 = __ballot(t == 1);
      unsigned long long m2 = __ballot(t == 2), m3 = __ballot(t == 3);
      unsigned long long m4 = __ballot(t == 4), m5 = __ballot(t == 5);
      unsigned long long m6 = __ballot(t == 6), m7 = __ballot(t == 7);
      // select own-class mask without dynamic array indexing (rule #20)
      unsigned long long x0 = (t & 1) ? m1 : m0, x1 = (t & 1) ? m3 : m2;
      unsigned long long x2 = (t & 1) ? m5 : m4, x3 = (t & 1) ? m7 : m6;
      unsigned long long y0 = (t & 2) ? x1 : x0, y1 = (t & 2) ? x3 : x2;
      unsigned long long mo = (t & 4) ? y1 : y0;
      rank[s] = __popcll(mo & ((1ull << lane) - 1ull));
      if (lane == 0) {
        int g = w * 4 + s;
        gcnt[g][0] = __popcll(m0); gcnt[g][1] = __popcll(m1);
        gcnt[g][2] = __popcll(m2); gcnt[g][3] = __popcll(m3);
        gcnt[g][4] = __popcll(m4); gcnt[g][5] = __popcll(m5);
        gcnt[g][6] = __popcll(m6); gcnt[g][7] = __popcll(m7);
      }
    }
    __syncthreads();
    if (tid < NCLS) {               // lanes 0..7 of wave 0: scan + 1 atomic instr
      int run = 0;
#pragma unroll
      for (int g = 0; g < 16; g++) { gpre[g][tid] = run; run += gcnt[g][tid]; }
      gbase[tid] = run ? atomicAdd(&hdr[tid], run) : 0;
    }
    __syncthreads();
    int i0 = (sb * 256 + tid) * 4;
#pragma unroll
    for (int s = 0; s < 4; s++) {
      int t = tcl[s];
      int g = w * 4 + s;
      sortedIdx[t * CAP + gbase[t] + gpre[g][t] + rank[s]] = i0 + s;
    }
  }
}

// ---------------- main MLP kernel ----------------
// 256 threads = 4 waves; wave w owns j in [w*64, w*64+64) (jf=0..3).
// Per-wave phase length IDENTICAL to the 56µs config (64 MFMA/layer/wave);
// but ~6 independent 4-wave blocks/CU (21KB LDS, ~80 unified regs) give the
// CU phase diversity to fill barrier idle — R4 had only ~3 barrier domains.
// Abuf (B-frags): [k/8][m][k%8]. MFMA: A=weights, B=activations -> C[j][m].
__device__ __forceinline__ void mfma_layer_T(
    unsigned short (*__restrict__ Abuf)[MT][8],
    const unsigned short* __restrict__ Apack,   // [k/8][256][8] frags
    const float* __restrict__ biasp,            // [256] prescaled
    int tid) {
  int lane = tid & 63, w = tid >> 6;            // w in 0..3
  int quad = lane >> 4, l16 = lane & 15;
  int jcol = w * 64 + l16;
  const bf16x8* __restrict__ Af = (const bf16x8*)Apack;  // frag idx = kq*256 + j

  f32x4 acc[4][2];  // [jf][mt]
#pragma unroll
  for (int jf = 0; jf < 4; jf++) {
    f32x4 bv = *(const f32x4*)&biasp[w * 64 + jf * 16 + quad * 4];
#pragma unroll
    for (int mt = 0; mt < 2; mt++) acc[jf][mt] = bv;
  }

  __builtin_amdgcn_s_setprio(1);
#pragma unroll
  for (int kb = 0; kb < 8; kb++) {
    int kq = kb * 4 + quad;
    bf16x8 af[4], bfr[2];
#pragma unroll
    for (int jf = 0; jf < 4; jf++) af[jf] = Af[kq * 256 + jcol + jf * 16];
#pragma unroll
    for (int mt = 0; mt < 2; mt++)
      bfr[mt] = *(const bf16x8*)&Abuf[kq][mt * 16 + l16][0];
#pragma unroll
    for (int jf = 0; jf < 4; jf++)
#pragma unroll
      for (int mt = 0; mt < 2; mt++)
        acc[jf][mt] = __builtin_amdgcn_mfma_f32_16x16x32_bf16(af[jf], bfr[mt], acc[jf][mt], 0, 0, 0);
  }
  __builtin_amdgcn_s_setprio(0);

  __syncthreads();  // all reads done block-wide; safe to overwrite in place

#pragma unroll
  for (int jf = 0; jf < 4; jf++) {
    int jbase = w * 64 + jf * 16 + quad * 4;  // 4 consecutive j per lane
#pragma unroll
    for (int mt = 0; mt < 2; mt++) {
      float t0 = tanh_p2(acc[jf][mt][0]);
      float t1 = tanh_p2(acc[jf][mt][1]);
      float t2 = tanh_p2(acc[jf][mt][2]);
      float t3 = tanh_p2(acc[jf][mt][3]);
      uint2 pk = make_uint2(pack_bf16(t0, t1), pack_bf16(t2, t3));
      *(uint2*)&Abuf[jbase >> 3][mt * 16 + l16][jbase & 7] = pk;
    }
  }
}

__global__ __launch_bounds__(256, 6) void k_mlp(
    const float* __restrict__ pos,
    const int* __restrict__ hdr, const int* __restrict__ sortedIdx,
    const unsigned short* __restrict__ packed23,
    const float* __restrict__ w1p, const float* __restrict__ b2p,
    const float* __restrict__ b3p, const float* __restrict__ b4p,
    const unsigned short* __restrict__ W4p,
    float* __restrict__ out) {

  __shared__ __align__(16) unsigned short Abuf[32][MT][8];  // 16 KB
  __shared__ __align__(16) float4 w1i[256];                 // 4 KB
  __shared__ __align__(16) float4 xpos4[MT];                // 512 B
  __shared__ int sIdx[MT];

  int b = blockIdx.x;
  int tid = threadIdx.x;

  // derive (class, tile) from per-class counts
  int c = -1, t0 = 0, cnt = 0;
  {
    int ts = 0;
#pragma unroll
    for (int cc = 0; cc < NCLS; cc++) {
      int cc_cnt = hdr[cc];
      int tiles = (cc_cnt + MT - 1) >> 5;
      if (b >= ts && b < ts + tiles) { c = cc; t0 = b - ts; cnt = cc_cnt; }
      ts += tiles;
    }
  }
  if (c < 0) return;
  int base = c * CAP + t0 * MT;
  int mCount = min(MT, cnt - t0 * MT);

  if (tid < MT) sIdx[tid] = sortedIdx[base + min(tid, mCount - 1)];
  w1i[tid] = ((const float4*)(w1p + (size_t)c * 1024))[tid];
  __syncthreads();
  if (tid < MT) {
    int idx = sIdx[tid] * 3;
    xpos4[tid] = make_float4(pos[idx], pos[idx + 1], pos[idx + 2], 0.0f);
  }
  __syncthreads();

  // ---- layer 1 (fp32 VALU): 8 thread-groups of 32, each covers 32 j ----
  {
    int m = tid & (MT - 1), q = tid >> 5;   // q in 0..7
    float4 xp = xpos4[m];
#pragma unroll
    for (int i8 = 0; i8 < 4; i8++) {
      int j8 = q * 4 + i8;            // group of 8 j
      unsigned pk[4];
#pragma unroll
      for (int jp = 0; jp < 4; jp++) {
        float t[2];
#pragma unroll
        for (int u = 0; u < 2; u++) {
          float4 wv = w1i[j8 * 8 + jp * 2 + u];
          float a = fmaf(xp.x, wv.x, fmaf(xp.y, wv.y, fmaf(xp.z, wv.z, wv.w)));
          t[u] = tanh_p2(a);
        }
        pk[jp] = pack_bf16(t[0], t[1]);
      }
      *(uint4*)&Abuf[j8][m][0] = make_uint4(pk[0], pk[1], pk[2], pk[3]);
    }
  }
  __syncthreads();

  // ---- layers 2,3 (MFMA, in-place) ----
  mfma_layer_T(Abuf, packed23 + ((size_t)c << 16), b2p + c * 256, tid);
  __syncthreads();
  mfma_layer_T(Abuf, packed23 + ((size_t)(8 + c) << 16), b3p + c * 256, tid);
  __syncthreads();

  // ---- layer 4 (MFMA, j padded 3->16): waves 0,1 handle the 2 m-subtiles ----
  {
    int lane = tid & 63, w = tid >> 6;
    if (w < 2) {
      int quad = lane >> 4, l16 = lane & 15;
      const bf16x8* __restrict__ W4f = (const bf16x8*)W4p;
      f32x4 acc = *(const f32x4*)&b4p[c * 16 + quad * 4];
      __builtin_amdgcn_s_setprio(1);
#pragma unroll
      for (int kb = 0; kb < 8; kb++) {
        int kq = kb * 4 + quad;
        bf16x8 a4 = W4f[(size_t)c * 512 + kq * 16 + l16];
        bf16x8 b4f = *(const bf16x8*)&Abuf[kq][w * 16 + l16][0];
        acc = __builtin_amdgcn_mfma_f32_16x16x32_bf16(a4, b4f, acc, 0, 0, 0);
      }
      __builtin_amdgcn_s_setprio(0);
      int m = w * 16 + l16;
      if (quad == 0 && m < mCount) {
        int o = sIdx[m] * 3;
        out[o + 0] = tanh_p2(acc[0]);
        out[o + 1] = tanh_p2(acc[1]);
        out[o + 2] = tanh_p2(acc[2]);
      }
    }
  }
}

extern "C" void kernel_launch(void* const* d_in, const int* in_sizes, int n_in,
                              void* d_out, int out_size, void* d_ws, size_t ws_size,
                              hipStream_t stream) {
  const float* pos = (const float*)d_in[0];
  const int* times = (const int*)d_in[1];
  const float* W1 = (const float*)d_in[2];
  const float* b1 = (const float*)d_in[3];
  const float* W2 = (const float*)d_in[4];
  const float* b2 = (const float*)d_in[5];
  const float* W3 = (const float*)d_in[6];
  const float* b3 = (const float*)d_in[7];
  const float* W4 = (const float*)d_in[8];
  const float* b4 = (const float*)d_in[9];

  char* ws = (char*)d_ws;
  int* hdr = (int*)ws;                                   // 64 B
  int* sortedIdx = (int*)(ws + 4096);                    // 8*CAP*4 = 1 MB
  float* w1p = (float*)(ws + 1052672);                   // 32 KB
  float* b2p = (float*)(ws + 1085440);                   // 8 KB
  float* b3p = (float*)(ws + 1093632);                   // 8 KB
  float* b4p = (float*)(ws + 1101824);                   // 512 B
  unsigned short* W4p = (unsigned short*)(ws + 1102336); // 64 KB
  unsigned short* packed23 = (unsigned short*)(ws + (2u << 20)); // 2 MB
  float* out = (float*)d_out;

  hipMemsetAsync(d_ws, 0, 64, stream);
  k_prep<<<PREP_GRID, 256, 0, stream>>>(times, W1, b1, W2, b2, W3, b3, W4, b4,
                                        hdr, sortedIdx, packed23,
                                        w1p, b2p, b3p, b4p, W4p);
  k_mlp<<<N_PTS / MT + NCLS, 256, 0, stream>>>(
      pos, hdr, sortedIdx, packed23, w1p, b2p, b3p, b4p, W4p, out);
}

// Round 10
// 128.161 us; speedup vs baseline: 1.0380x; 1.0380x over previous
//
#include <hip/hip_runtime.h>
#include <stdint.h>

#define N_PTS 131072
#define NCLS 8
#define HID 256
#define MT 64      // points per tile; 38.4KB LDS, ~2-3 blocks/CU — measured local optimum
#define CAP 32768  // per-class sortedIdx capacity (counts ~16.4k for this input)

// prescale: tanh(z) computed as 1 - 2/(exp2(PSC*z)+1), PSC = 2*log2(e)
#define PSC 2.8853900817779268f

typedef __bf16 bf16x8 __attribute__((ext_vector_type(8)));
typedef float f32x4 __attribute__((ext_vector_type(4)));

// tanh from a = PSC*z: tanh = 1 - 2/(2^a + 1); v_exp_f32 is 2^x natively
__device__ __forceinline__ float tanh_p2(float a) {
  return fmaf(-2.0f, __builtin_amdgcn_rcpf(__builtin_amdgcn_exp2f(a) + 1.0f), 1.0f);
}

__device__ __forceinline__ unsigned short f2bf_rne(float f) {
  unsigned u = __float_as_uint(f);
  u = u + 0x7fffu + ((u >> 16) & 1u);
  return (unsigned short)(u >> 16);
}

// pack two floats to bf16 pair (round-half-up): {hi16(b), hi16(a)}
__device__ __forceinline__ unsigned pack_bf16(float a, float b) {
  unsigned ua = __float_as_uint(a) + 0x8000u;
  unsigned ub = __float_as_uint(b) + 0x8000u;
  return __builtin_amdgcn_perm(ub, ua, 0x07060302u);
}

// ---------------- fused prep kernel ----------------
// ws header (ints): [0..7] = per-class cursors (become counts). memset to 0.
// Block partition: [0,256) packed23 tiles; [256,433) misc pack; [433,561) scatter.
// packed23: bf16 [l(2)][c][k/8][j][k%8] — A-operand frags, value = PSC*W[k][j]
#define PK_TILES 256
#define MISC_BLKS 177
#define MISC_N 45184
#define SCAT_BLKS 128   // 1024 points/block, ballot-ranked, 1 atomic instr/block
#define PREP_GRID (PK_TILES + MISC_BLKS + SCAT_BLKS)

__global__ __launch_bounds__(256) void k_prep(
    const int* __restrict__ times,
    const float* __restrict__ W1, const float* __restrict__ b1,
    const float* __restrict__ W2, const float* __restrict__ b2,
    const float* __restrict__ W3, const float* __restrict__ b3,
    const float* __restrict__ W4, const float* __restrict__ b4,
    int* __restrict__ hdr, int* __restrict__ sortedIdx,
    unsigned short* __restrict__ packed23,
    float* __restrict__ w1p, float* __restrict__ b2p,
    float* __restrict__ b3p, float* __restrict__ b4p,
    unsigned short* __restrict__ W4p) {
  __shared__ unsigned short T[64][64];  // 8 KB transpose tile

  int b = blockIdx.x;
  int tid = threadIdx.x;

  if (b < PK_TILES) {
    // ---- tiled transpose-pack of W2/W3 into MFMA A-frag layout ----
    int cl = b >> 4;            // 0..15 class-layer
    int l = cl >> 3, c = cl & 7;
    int tile = b & 15;
    int k0 = (tile >> 2) * 64, j0 = (tile & 3) * 64;
    const float* W = (l ? W3 : W2) + c * 65536;
#pragma unroll
    for (int it = 0; it < 4; it++) {
      int f = tid + it * 256;        // 0..1023 float4 slots
      int row = f >> 4, cg = f & 15;
      float4 v = *(const float4*)&W[(k0 + row) * 256 + j0 + cg * 4];
      T[row][cg * 4 + 0] = f2bf_rne(PSC * v.x);
      T[row][cg * 4 + 1] = f2bf_rne(PSC * v.y);
      T[row][cg * 4 + 2] = f2bf_rne(PSC * v.z);
      T[row][cg * 4 + 3] = f2bf_rne(PSC * v.w);
    }
    __syncthreads();
#pragma unroll
    for (int it = 0; it < 2; it++) {
      int g = tid + it * 256;        // 0..511: kb = g>>6, j = g&63
      int kb = g >> 6, j = g & 63;
      unsigned u[8];
#pragma unroll
      for (int uu = 0; uu < 8; uu++) u[uu] = T[kb * 8 + uu][j];
      uint4 pk = make_uint4(u[0] | (u[1] << 16), u[2] | (u[3] << 16),
                            u[4] | (u[5] << 16), u[6] | (u[7] << 16));
      int base = cl * 65536 + (((k0 >> 3) + kb) * 256 + (j0 + j)) * 8;
      *(uint4*)&packed23[base] = pk;
    }
  } else if (b < PK_TILES + MISC_BLKS) {
    // ---- misc pack: w1p, b2p, b3p, b4p, W4p (all prescaled by PSC) ----
    int e2 = (b - PK_TILES) * 256 + tid;
    if (e2 < 8192) {          // w1p: [c][j][4] = {w0,w1,w2,b} * PSC
      int c = e2 >> 10, rem = e2 & 1023;
      int j = rem >> 2, t = rem & 3;
      float v = (t < 3) ? W1[c * 768 + t * 256 + j] : b1[c * 256 + j];
      w1p[e2] = PSC * v;
    } else if (e2 < 10240) {
      int i = e2 - 8192;
      b2p[i] = PSC * b2[i];
    } else if (e2 < 12288) {
      int i = e2 - 10240;
      b3p[i] = PSC * b3[i];
    } else if (e2 < 12416) {  // b4p: [c][16]
      int i = e2 - 12288;
      int c = i >> 4, r = i & 15;
      b4p[i] = (r < 3) ? PSC * b4[c * 3 + r] : 0.0f;
    } else if (e2 < MISC_N) { // W4p: [c][k/8][j(16)][k%8]
      int i = e2 - 12416;
      int c = i >> 12, rem = i & 4095;
      int jj = rem & 7, j = (rem >> 3) & 15, k = ((rem >> 7) << 3) + jj;
      float v = (j < 3) ? PSC * W4[c * 768 + k * 3 + j] : 0.0f;
      W4p[c * 4096 + rem] = f2bf_rne(v);
    }
  } else {
    // ---- scatter-append: ballot-ranked, zero LDS atomics,
    //      ONE global-atomic instruction per block (8 lanes, hdr[0..7]) ----
    __shared__ int gcnt[16][NCLS];  // per (wave,slot) histograms
    __shared__ int gpre[16][NCLS];  // exclusive prefix per class
    __shared__ int gbase[NCLS];     // block base in global per-class region
    int sb = b - (PK_TILES + MISC_BLKS);
    int lane = tid & 63, w = tid >> 6;
    int4 tv = ((const int4*)times)[sb * 256 + tid];  // 4 points per thread
    int tcl[4] = {tv.x, tv.y, tv.z, tv.w};
    int rank[4];
#pragma unroll
    for (int s = 0; s < 4; s++) {
      int t = tcl[s];
      unsigned long long m0 = __ballot(t == 0), m1 = __ballot(t == 1);
      unsigned long long m2 = __ballot(t == 2), m3 = __ballot(t == 3);
      unsigned long long m4 = __ballot(t == 4), m5 = __ballot(t == 5);
      unsigned long long m6 = __ballot(t == 6), m7 = __ballot(t == 7);
      // select own-class mask without dynamic array indexing (rule #20)
      unsigned long long x0 = (t & 1) ? m1 : m0, x1 = (t & 1) ? m3 : m2;
      unsigned long long x2 = (t & 1) ? m5 : m4, x3 = (t & 1) ? m7 : m6;
      unsigned long long y0 = (t & 2) ? x1 : x0, y1 = (t & 2) ? x3 : x2;
      unsigned long long mo = (t & 4) ? y1 : y0;
      rank[s] = __popcll(mo & ((1ull << lane) - 1ull));
      if (lane == 0) {
        int g = w * 4 + s;
        gcnt[g][0] = __popcll(m0); gcnt[g][1] = __popcll(m1);
        gcnt[g][2] = __popcll(m2); gcnt[g][3] = __popcll(m3);
        gcnt[g][4] = __popcll(m4); gcnt[g][5] = __popcll(m5);
        gcnt[g][6] = __popcll(m6); gcnt[g][7] = __popcll(m7);
      }
    }
    __syncthreads();
    if (tid < NCLS) {               // lanes 0..7 of wave 0: scan + 1 atomic instr
      int run = 0;
#pragma unroll
      for (int g = 0; g < 16; g++) { gpre[g][tid] = run; run += gcnt[g][tid]; }
      gbase[tid] = run ? atomicAdd(&hdr[tid], run) : 0;
    }
    __syncthreads();
    int i0 = (sb * 256 + tid) * 4;
#pragma unroll
    for (int s = 0; s < 4; s++) {
      int t = tcl[s];
      int g = w * 4 + s;
      sortedIdx[t * CAP + gbase[t] + gpre[g][t] + rank[s]] = i0 + s;
    }
  }
}

// ---------------- main MLP kernel ----------------
// 512 threads = 8 waves; wave w owns j in [w*32, w*32+32) (jf=0,1).
// Abuf (B-frags): [k/8][m][k%8]. MFMA: A=weights, B=activations -> C[j][m];
// lane holds 4 consecutive j at fixed m -> epilogue ds_write_b64, no transpose.
// NOTE (session ledger): MT=64/512thr/(512,6) is the measured optimum. Falsified
// alternatives: MT=128 (75µs, residency), MT=32@512 (76µs), MT=32@256 (62µs),
// 32x32x16 MFMA (59µs), (512,4) reg headroom (62µs). Do not re-try without
// new counter evidence.
struct AfPre { bf16x8 a0, a1; };  // prefetched A-frags (pure global, no LDS dep)

__device__ __forceinline__ void mfma_layer_T(
    unsigned short (*__restrict__ Abuf)[MT][8],
    const unsigned short* __restrict__ Apack,   // [k/8][256][8] frags
    const float* __restrict__ biasp,            // [256] prescaled
    int tid, const AfPre& pre,
    const bf16x8* __restrict__ np0, const bf16x8* __restrict__ np1,
    AfPre& nxt) {
  int lane = tid & 63, w = tid >> 6;
  int quad = lane >> 4, l16 = lane & 15;
  int jcol = w * 32 + l16;
  const bf16x8* __restrict__ Af = (const bf16x8*)Apack;  // frag idx = kq*256 + j

  f32x4 acc[2][4];  // [jf][mt]
#pragma unroll
  for (int jf = 0; jf < 2; jf++) {
    f32x4 bv = *(const f32x4*)&biasp[w * 32 + jf * 16 + quad * 4];
#pragma unroll
    for (int mt = 0; mt < 4; mt++) acc[jf][mt] = bv;
  }

  __builtin_amdgcn_s_setprio(1);
#pragma unroll
  for (int kb = 0; kb < 8; kb++) {
    int kq = kb * 4 + quad;
    bf16x8 af[2], bfr[4];
    if (kb == 0) {
      af[0] = pre.a0; af[1] = pre.a1;   // prefetched one phase earlier
    } else {
#pragma unroll
      for (int jf = 0; jf < 2; jf++) af[jf] = Af[kq * 256 + jcol + jf * 16];
    }
#pragma unroll
    for (int mt = 0; mt < 4; mt++)
      bfr[mt] = *(const bf16x8*)&Abuf[kq][mt * 16 + l16][0];
#pragma unroll
    for (int jf = 0; jf < 2; jf++)
#pragma unroll
      for (int mt = 0; mt < 4; mt++)
        acc[jf][mt] = __builtin_amdgcn_mfma_f32_16x16x32_bf16(af[jf], bfr[mt], acc[jf][mt], 0, 0, 0);
  }
  __builtin_amdgcn_s_setprio(0);

  // prefetch next phase's kb=0 A-frags: overlaps barrier + tanh epilogue
  nxt.a0 = *np0;
  nxt.a1 = *np1;

  __syncthreads();  // all reads done block-wide; safe to overwrite in place

#pragma unroll
  for (int jf = 0; jf < 2; jf++) {
    int jbase = w * 32 + jf * 16 + quad * 4;  // 4 consecutive j per lane
#pragma unroll
    for (int mt = 0; mt < 4; mt++) {
      float t0 = tanh_p2(acc[jf][mt][0]);
      float t1 = tanh_p2(acc[jf][mt][1]);
      float t2 = tanh_p2(acc[jf][mt][2]);
      float t3 = tanh_p2(acc[jf][mt][3]);
      uint2 pk = make_uint2(pack_bf16(t0, t1), pack_bf16(t2, t3));
      *(uint2*)&Abuf[jbase >> 3][mt * 16 + l16][jbase & 7] = pk;
    }
  }
}

__global__ __launch_bounds__(512, 6) void k_mlp(
    const float* __restrict__ pos,
    const int* __restrict__ hdr, const int* __restrict__ sortedIdx,
    const unsigned short* __restrict__ packed23,
    const float* __restrict__ w1p, const float* __restrict__ b2p,
    const float* __restrict__ b3p, const float* __restrict__ b4p,
    const unsigned short* __restrict__ W4p,
    float* __restrict__ out) {

  __shared__ __align__(16) unsigned short Abuf[32][MT][8];  // 32 KB
  __shared__ __align__(16) float4 w1i[256];                 // 4 KB
  __shared__ __align__(16) float4 xpos4[MT];
  __shared__ int sIdx[MT];

  int b = blockIdx.x;
  int tid = threadIdx.x;

  // derive (class, tile) from per-class counts
  int c = -1, t0 = 0, cnt = 0;
  {
    int ts = 0;
#pragma unroll
    for (int cc = 0; cc < NCLS; cc++) {
      int cc_cnt = hdr[cc];
      int tiles = (cc_cnt + MT - 1) >> 6;
      if (b >= ts && b < ts + tiles) { c = cc; t0 = b - ts; cnt = cc_cnt; }
      ts += tiles;
    }
  }
  if (c < 0) return;
  int base = c * CAP + t0 * MT;
  int mCount = min(MT, cnt - t0 * MT);

  int lane = tid & 63, w = tid >> 6;
  int quad = lane >> 4, l16 = lane & 15;
  int jcol = w * 32 + l16;

  if (tid < MT) sIdx[tid] = sortedIdx[base + min(tid, mCount - 1)];
  if (tid < 256) w1i[tid] = ((const float4*)(w1p + (size_t)c * 1024))[tid];
  __syncthreads();
  if (tid < MT) {
    int idx = sIdx[tid] * 3;
    xpos4[tid] = make_float4(pos[idx], pos[idx + 1], pos[idx + 2], 0.0f);
  }

  // prefetch layer-2 kb=0 A-frags (hides under layer-1 VALU compute)
  const bf16x8* __restrict__ Af2 = (const bf16x8*)(packed23 + ((size_t)c << 16));
  const bf16x8* __restrict__ Af3 = (const bf16x8*)(packed23 + ((size_t)(8 + c) << 16));
  const bf16x8* __restrict__ W4f = (const bf16x8*)W4p;
  AfPre pre2, pre3, pre4;
  pre2.a0 = Af2[quad * 256 + jcol];
  pre2.a1 = Af2[quad * 256 + jcol + 16];
  __syncthreads();

  // ---- layer 1 (fp32 VALU): each wave covers 32 j ----
  {
    int m = tid & 63, q = tid >> 6;   // q in 0..7
    float4 xp = xpos4[m];
#pragma unroll
    for (int i8 = 0; i8 < 4; i8++) {
      int j8 = q * 4 + i8;            // group of 8 j
      unsigned pk[4];
#pragma unroll
      for (int jp = 0; jp < 4; jp++) {
        float t[2];
#pragma unroll
        for (int u = 0; u < 2; u++) {
          float4 wv = w1i[j8 * 8 + jp * 2 + u];
          float a = fmaf(xp.x, wv.x, fmaf(xp.y, wv.y, fmaf(xp.z, wv.z, wv.w)));
          t[u] = tanh_p2(a);
        }
        pk[jp] = pack_bf16(t[0], t[1]);
      }
      *(uint4*)&Abuf[j8][m][0] = make_uint4(pk[0], pk[1], pk[2], pk[3]);
    }
  }
  __syncthreads();

  // ---- layers 2,3 (MFMA, in-place); each prefetches the next phase's frags ----
  mfma_layer_T(Abuf, packed23 + ((size_t)c << 16), b2p + c * 256, tid, pre2,
               &Af3[quad * 256 + jcol], &Af3[quad * 256 + jcol + 16], pre3);
  __syncthreads();
  mfma_layer_T(Abuf, packed23 + ((size_t)(8 + c) << 16), b3p + c * 256, tid, pre3,
               &W4f[(size_t)c * 512 + quad * 16 + l16],
               &W4f[(size_t)c * 512 + (quad + 4) * 16 + l16], pre4);
  __syncthreads();

  // ---- layer 4 (MFMA, j padded 3->16): waves 0..3 handle m-tiles ----
  {
    if (w < 4) {
      f32x4 acc = *(const f32x4*)&b4p[c * 16 + quad * 4];
      __builtin_amdgcn_s_setprio(1);
#pragma unroll
      for (int kb = 0; kb < 8; kb++) {
        int kq = kb * 4 + quad;
        bf16x8 a4;
        if (kb == 0) a4 = pre4.a0;
        else if (kb == 1) a4 = pre4.a1;
        else a4 = W4f[(size_t)c * 512 + kq * 16 + l16];
        bf16x8 b4f = *(const bf16x8*)&Abuf[kq][w * 16 + l16][0];
        acc = __builtin_amdgcn_mfma_f32_16x16x32_bf16(a4, b4f, acc, 0, 0, 0);
      }
      __builtin_amdgcn_s_setprio(0);
      int m = w * 16 + l16;
      if (quad == 0 && m < mCount) {
        int o = sIdx[m] * 3;
        out[o + 0] = tanh_p2(acc[0]);
        out[o + 1] = tanh_p2(acc[1]);
        out[o + 2] = tanh_p2(acc[2]);
      }
    }
  }
}

extern "C" void kernel_launch(void* const* d_in, const int* in_sizes, int n_in,
                              void* d_out, int out_size, void* d_ws, size_t ws_size,
                              hipStream_t stream) {
  const float* pos = (const float*)d_in[0];
  const int* times = (const int*)d_in[1];
  const float* W1 = (const float*)d_in[2];
  const float* b1 = (const float*)d_in[3];
  const float* W2 = (const float*)d_in[4];
  const float* b2 = (const float*)d_in[5];
  const float* W3 = (const float*)d_in[6];
  const float* b3 = (const float*)d_in[7];
  const float* W4 = (const float*)d_in[8];
  const float* b4 = (const float*)d_in[9];

  char* ws = (char*)d_ws;
  int* hdr = (int*)ws;                                   // 64 B
  int* sortedIdx = (int*)(ws + 4096);                    // 8*CAP*4 = 1 MB
  float* w1p = (float*)(ws + 1052672);                   // 32 KB
  float* b2p = (float*)(ws + 1085440);                   // 8 KB
  float* b3p = (float*)(ws + 1093632);                   // 8 KB
  float* b4p = (float*)(ws + 1101824);                   // 512 B
  unsigned short* W4p = (unsigned short*)(ws + 1102336); // 64 KB
  unsigned short* packed23 = (unsigned short*)(ws + (2u << 20)); // 2 MB
  float* out = (float*)d_out;

  hipMemsetAsync(d_ws, 0, 64, stream);
  k_prep<<<PREP_GRID, 256, 0, stream>>>(times, W1, b1, W2, b2, W3, b3, W4, b4,
                                        hdr, sortedIdx, packed23,
                                        w1p, b2p, b3p, b4p, W4p);
  k_mlp<<<N_PTS / MT + NCLS, 512, 0, stream>>>(
      pos, hdr, sortedIdx, packed23, w1p, b2p, b3p, b4p, W4p, out);
}